// Round 7
// baseline (3302.422 us; speedup 1.0000x reference)
//
#include <hip/hip_runtime.h>
#include <hip/hip_bf16.h>
#include <math.h>

#define GRAPHS 128
#define SCAN_B 256
#define BM 128
#define BN 128
#define BK 64
#define PCH 128          // nodes per pooling block
#define HT_STRIDE 51200  // padded node stride for feature-major buffers (25*2048)

typedef __attribute__((ext_vector_type(8))) short bfrag8;   // 8 bf16 (4 VGPRs)
typedef __attribute__((ext_vector_type(4))) float f32x4;

__device__ inline unsigned short f2b(float f) {
    unsigned int u = __float_as_uint(f);
    unsigned int r = (u + 0x7fffu + ((u >> 16) & 1u)) >> 16;  // RNE
    return (unsigned short)r;
}
__device__ inline float b2f(unsigned short u) {
    return __uint_as_float(((unsigned int)u) << 16);
}
__device__ inline void unpack8(float* v, uint4 u) {
    v[0] = b2f(u.x & 0xffffu); v[1] = b2f(u.x >> 16);
    v[2] = b2f(u.y & 0xffffu); v[3] = b2f(u.y >> 16);
    v[4] = b2f(u.z & 0xffffu); v[5] = b2f(u.z >> 16);
    v[6] = b2f(u.w & 0xffffu); v[7] = b2f(u.w >> 16);
}

__device__ inline void gload16(const void* g, void* l) {
    typedef unsigned int __attribute__((address_space(1))) gu32;
    typedef unsigned int __attribute__((address_space(3))) su32;
    __builtin_amdgcn_global_load_lds((const gu32*)g, (su32*)l, 16, 0, 0);
}

// bijective XCD chunk-major remap (m204)
__device__ inline int xcd_vid(int p, int nwg) {
    int q = nwg >> 3, r = nwg & 7, x = p & 7, ix = p >> 3;
    return (x < r ? x * (q + 1) : r * (q + 1) + (x - r) * q) + ix;
}

// ---------------- CSR build ----------------

__global__ void k_count(const int* __restrict__ dst, int* __restrict__ cnt, int E) {
    int i = blockIdx.x * blockDim.x + threadIdx.x;
    if (i < E) atomicAdd(&cnt[dst[i]], 1);
}

__global__ void k_scan1(const int* __restrict__ cnt, int* __restrict__ excl,
                        int* __restrict__ bsum, int n) {
    __shared__ int sh[SCAN_B];
    int t = threadIdx.x;
    int i = blockIdx.x * SCAN_B + t;
    int v = (i < n) ? cnt[i] : 0;
    sh[t] = v;
    __syncthreads();
    for (int off = 1; off < SCAN_B; off <<= 1) {
        int x = (t >= off) ? sh[t - off] : 0;
        __syncthreads();
        sh[t] += x;
        __syncthreads();
    }
    if (i < n) excl[i] = sh[t] - v;
    if (t == SCAN_B - 1) bsum[blockIdx.x] = sh[t];
}

__global__ void k_scan2(int* __restrict__ bsum, int nb) {
    __shared__ int sh[SCAN_B];
    int t = threadIdx.x;
    int v = (t < nb) ? bsum[t] : 0;
    sh[t] = v;
    __syncthreads();
    for (int off = 1; off < SCAN_B; off <<= 1) {
        int x = (t >= off) ? sh[t - off] : 0;
        __syncthreads();
        sh[t] += x;
        __syncthreads();
    }
    if (t < nb) bsum[t] = sh[t] - v;
}

__global__ void k_scan3(int* __restrict__ rowstart, const int* __restrict__ bsum,
                        const int* __restrict__ cnt, float* __restrict__ dinv,
                        int* __restrict__ cursor, int n, int E) {
    int i = blockIdx.x * SCAN_B + threadIdx.x;
    if (i < n) {
        rowstart[i] += bsum[blockIdx.x];
        cursor[i] = 0;
        dinv[i] = rsqrtf((float)cnt[i] + 1.0f);  // +1 self loop
    }
    if (i == 0) rowstart[n] = E;
}

__global__ void k_scatter_csr(const int* __restrict__ src, const int* __restrict__ dst,
                              const int* __restrict__ rowstart, int* __restrict__ cursor,
                              unsigned short* __restrict__ csrc16, int E) {
    int e = blockIdx.x * blockDim.x + threadIdx.x;
    if (e >= E) return;
    int d = dst[e];
    int pos = rowstart[d] + atomicAdd(&cursor[d], 1);
    csrc16[pos] = (unsigned short)src[e];
}

// ---------------- weight transpose + bf16 cast: WT[n][k] = bf16(W[k][n]) ----------------

__global__ void k_wt(const float* __restrict__ W, unsigned short* __restrict__ WT,
                     int K, int N) {
    int idx = blockIdx.x * 256 + threadIdx.x;
    if (idx >= K * N) return;
    int k = idx / N, n2 = idx - k * N;
    WT[(size_t)n2 * K + k] = f2b(W[idx]);
}

// ---------------- x -> x_T [128][HT_STRIDE] bf16, pre-scaled by dinv ----------------

__global__ __launch_bounds__(256) void k_x2bT(const float* __restrict__ x,
                                              const float* __restrict__ dinv,
                                              unsigned short* __restrict__ xT, int n) {
    __shared__ unsigned short tx[128][66];
    const int n0 = blockIdx.x * 64;
    const int t = threadIdx.x;
#pragma unroll
    for (int it = 0; it < 8; ++it) {
        int idx = it * 256 + t;             // 2048 float4 chunks
        int r = idx >> 5, c4 = (idx & 31) * 4;
        float4 v = {0.f, 0.f, 0.f, 0.f};
        float d = 0.f;
        int row = n0 + r;
        if (row < n) { v = *(const float4*)(x + (size_t)row * 128 + c4); d = dinv[row]; }
        tx[c4 + 0][r] = f2b(v.x * d);
        tx[c4 + 1][r] = f2b(v.y * d);
        tx[c4 + 2][r] = f2b(v.z * d);
        tx[c4 + 3][r] = f2b(v.w * d);
    }
    __syncthreads();
    int f = t >> 1, half = t & 1;
    unsigned int ov[16];
#pragma unroll
    for (int j2 = 0; j2 < 16; ++j2) {
        int nn = half * 32 + j2 * 2;
        ov[j2] = (unsigned)tx[f][nn] | ((unsigned)tx[f][nn + 1] << 16);
    }
    unsigned short* op = xT + (size_t)f * HT_STRIDE + n0 + half * 32;
#pragma unroll
    for (int w = 0; w < 4; ++w) ((uint4*)op)[w] = *(uint4*)&ov[w * 4];
}

// ---------------- LDS-staged feature-major aggregation ----------------
// One block per feature f. Stage the pre-scaled row hT[f][0..HT_STRIDE) (100 KB) into
// LDS; each thread handles node octets q, q+512, ... (coalesced 16-B output stores).
// agg_T[f][i] = dinv[i] * (sum_{e:dst=i} lds[src_e] + lds[i]).

__global__ __launch_bounds__(512) void k_aggT(
    const unsigned short* __restrict__ hT, unsigned short* __restrict__ aggT,
    const int* __restrict__ rowstart, const unsigned short* __restrict__ csrc16,
    const float* __restrict__ dinv, int n, int mpad) {
    __shared__ unsigned short srow[HT_STRIDE];   // 102,400 B
    const int f = blockIdx.x;
    const int t = threadIdx.x;
    const unsigned short* src = hT + (size_t)f * HT_STRIDE;
#pragma unroll
    for (int it = 0; it < 12; ++it)   // 12*512*8 = 49152 elements
        gload16(src + it * 4096 + t * 8, (char*)srow + it * 8192 + t * 16);
    if (t < 256)                      // tail: 2048 elements (waves 0-3 only)
        gload16(src + 49152 + t * 8, (char*)srow + 98304 + t * 16);
    __syncthreads();

    unsigned short* orow = aggT + (size_t)f * HT_STRIDE;
    const int noct = mpad >> 3;       // 6256
    for (int q = t; q < noct; q += 512) {
        int i0 = q << 3;
        unsigned short ov[8];
        int rs0 = (i0 < n) ? rowstart[i0] : 0;
#pragma unroll
        for (int u = 0; u < 8; ++u) {
            int i = i0 + u;
            float sum = 0.f;
            if (i < n) {
                int rs1 = rowstart[i + 1];
                for (int j = rs0; j < rs1; ++j)
                    sum += b2f(srow[csrc16[j]]);
                sum = (sum + b2f(srow[i])) * dinv[i];
                rs0 = rs1;
            }
            ov[u] = f2b(sum);
        }
        *(uint4*)(orow + i0) = *(uint4*)ov;
    }
}

// ---------------- tiled transpose: agg_T [F][HT_STRIDE] -> agg [Mpad][F] ----------------

__global__ __launch_bounds__(256) void k_trT(const unsigned short* __restrict__ aggT,
                                             unsigned short* __restrict__ agg, int F) {
    __shared__ unsigned int tl[64][35];   // packed node-pairs, padded stride
    const int n0 = blockIdx.x * 64, f0 = blockIdx.y * 64;
    const int t = threadIdx.x;
#pragma unroll
    for (int it = 0; it < 2; ++it) {
        int idx = it * 256 + t;           // 512 chunks: 64 f-rows x 8
        int fr = idx >> 3, c8 = (idx & 7) * 8;
        uint4 v = *(const uint4*)(aggT + (size_t)(f0 + fr) * HT_STRIDE + n0 + c8);
        int cb = c8 >> 1;
        tl[fr][cb + 0] = v.x; tl[fr][cb + 1] = v.y;
        tl[fr][cb + 2] = v.z; tl[fr][cb + 3] = v.w;
    }
    __syncthreads();
#pragma unroll
    for (int it = 0; it < 2; ++it) {
        int nr = (t >> 3) + it * 32, fc = (t & 7) * 8;
        unsigned short o[8];
#pragma unroll
        for (int j = 0; j < 8; ++j) {
            unsigned int p = tl[fc + j][nr >> 1];
            o[j] = (nr & 1) ? (unsigned short)(p >> 16) : (unsigned short)(p & 0xffffu);
        }
        *(uint4*)(agg + (size_t)(n0 + nr) * F + f0 + fc) = *(uint4*)o;
    }
}

// ---------------- bf16 MFMA GEMM: Z = A @ BT^T + bias (bf16 out), XCD-chunked ----------

__global__ __launch_bounds__(256) void k_gemm_bf16(
    const unsigned short* __restrict__ A, const unsigned short* __restrict__ BT,
    const float* __restrict__ bias, unsigned short* __restrict__ C,
    int K, int N, int ncb) {
    __shared__ __align__(16) char sA[BM * BK * 2];
    __shared__ __align__(16) char sB[BN * BK * 2];

    const int vid = xcd_vid((int)blockIdx.x, (int)gridDim.x);
    const int rb = vid / ncb;
    const int cb = vid - rb * ncb;
    const int tid = threadIdx.x;
    const int lane = tid & 63;
    const int wave = tid >> 6;
    const int wr = wave >> 1, wc = wave & 1;
    const size_t row0 = (size_t)rb * BM;
    const size_t col0 = (size_t)cb * BN;

    const unsigned short* srcA[4];
    const unsigned short* srcB[4];
    char* dstA[4];
    char* dstB[4];
#pragma unroll
    for (int c = 0; c < 4; ++c) {
        int idx = c * 256 + tid;
        int row = idx >> 3;
        int cbl = ((idx & 7) << 4) ^ ((row & 7) << 4);
        srcA[c] = A + (row0 + row) * K + (cbl >> 1);
        srcB[c] = BT + (col0 + row) * K + (cbl >> 1);
        dstA[c] = sA + idx * 16;
        dstB[c] = sB + idx * 16;
    }

    const int fr = lane & 15;
    const int fg = lane >> 4;
    const int fsw = (lane & 7) << 4;
    int offA[4][2], offB[4][2];
#pragma unroll
    for (int t = 0; t < 4; ++t)
#pragma unroll
        for (int kk = 0; kk < 2; ++kk) {
            offA[t][kk] = (wr * 64 + t * 16 + fr) * (BK * 2) + ((kk * 64 + fg * 16) ^ fsw);
            offB[t][kk] = (wc * 64 + t * 16 + fr) * (BK * 2) + ((kk * 64 + fg * 16) ^ fsw);
        }

    f32x4 acc[4][4] = {};

    for (int k0 = 0; k0 < K; k0 += BK) {
#pragma unroll
        for (int c = 0; c < 4; ++c) gload16(srcA[c] + k0, dstA[c]);
#pragma unroll
        for (int c = 0; c < 4; ++c) gload16(srcB[c] + k0, dstB[c]);
        __syncthreads();
#pragma unroll
        for (int kk = 0; kk < 2; ++kk) {
            bfrag8 av[4], bv[4];
#pragma unroll
            for (int t = 0; t < 4; ++t) av[t] = *(const bfrag8*)(sA + offA[t][kk]);
#pragma unroll
            for (int t = 0; t < 4; ++t) bv[t] = *(const bfrag8*)(sB + offB[t][kk]);
#pragma unroll
            for (int i = 0; i < 4; ++i)
#pragma unroll
                for (int j = 0; j < 4; ++j)
                    acc[i][j] = __builtin_amdgcn_mfma_f32_16x16x32_bf16(av[i], bv[j],
                                                                        acc[i][j], 0, 0, 0);
        }
        __syncthreads();
    }

#pragma unroll
    for (int i = 0; i < 4; ++i) {
#pragma unroll
        for (int j = 0; j < 4; ++j) {
            size_t r = row0 + wr * 64 + i * 16 + fg * 4;
            size_t cc = col0 + wc * 64 + j * 16 + fr;
            float bb = bias[cc];
#pragma unroll
            for (int q = 0; q < 4; ++q)
                C[(r + q) * N + cc] = f2b(acc[i][j][q] + bb);
        }
    }
}

// ---------------- LN(+LeakyReLU) with transposed pre-scaled output ----------------
// Reads z [Mpad][F] node-major tile (64 nodes), writes hT[f][n0..n0+64) = dinv[n]*h[n][f].

template <int F, bool LRELU>
__global__ __launch_bounds__(256) void k_ln2t(
    const unsigned short* __restrict__ z, unsigned short* __restrict__ hT,
    const float* __restrict__ g, const float* __restrict__ be,
    const float* __restrict__ dinv, int n) {
    constexpr int LW = F + 8;
    __shared__ unsigned short tz[64][LW];
    __shared__ float smu[64], srs[64], sdv[64];
    const int n0 = blockIdx.x * 64;
    const int t = threadIdx.x;

    constexpr int CH = 64 * (F / 8) / 256;   // 16 (F=512) / 8 (F=256)
#pragma unroll
    for (int it = 0; it < CH; ++it) {
        int idx = it * 256 + t;
        int r = idx / (F / 8);
        int c8 = (idx % (F / 8)) * 8;
        uint4 v = {0u, 0u, 0u, 0u};
        int row = n0 + r;
        if (row < n) v = *(const uint4*)(z + (size_t)row * F + c8);
        *(uint4*)&tz[r][c8] = v;
    }
    __syncthreads();
    {
        int r = t >> 2, quad = t & 3;
        float s = 0.f, q = 0.f;
        const int seg = F / 4;
        for (int c = quad * seg; c < quad * seg + seg; c += 8) {
            uint4 u = *(const uint4*)&tz[r][c];
            float v[8]; unpack8(v, u);
#pragma unroll
            for (int k2 = 0; k2 < 8; ++k2) { s += v[k2]; q += v[k2] * v[k2]; }
        }
        s += __shfl_xor(s, 1); q += __shfl_xor(q, 1);
        s += __shfl_xor(s, 2); q += __shfl_xor(q, 2);
        if (quad == 0) {
            float mu = s * (1.0f / F);
            float var = q * (1.0f / F) - mu * mu;
            smu[r] = mu;
            srs[r] = rsqrtf(var + 1e-5f);
            int row = n0 + r;
            sdv[r] = (row < n) ? dinv[row] : 0.f;
        }
    }
    __syncthreads();
    constexpr int FPT = (F + 255) / 256;
#pragma unroll
    for (int ff = 0; ff < FPT; ++ff) {
        int f = t + ff * 256;
        if (f >= F) break;
        float gf = g[f], bef = be[f];
        unsigned int ov[32];
#pragma unroll 8
        for (int j2 = 0; j2 < 32; ++j2) {
            float v0 = b2f(tz[2 * j2][f]);
            float y0 = (v0 - smu[2 * j2]) * srs[2 * j2] * gf + bef;
            if (LRELU) y0 = fmaxf(y0, 0.f) + 0.01f * fminf(y0, 0.f);
            y0 *= sdv[2 * j2];
            float v1 = b2f(tz[2 * j2 + 1][f]);
            float y1 = (v1 - smu[2 * j2 + 1]) * srs[2 * j2 + 1] * gf + bef;
            if (LRELU) y1 = fmaxf(y1, 0.f) + 0.01f * fminf(y1, 0.f);
            y1 *= sdv[2 * j2 + 1];
            ov[j2] = (unsigned)f2b(y0) | ((unsigned)f2b(y1) << 16);
        }
        unsigned short* op = hT + (size_t)f * HT_STRIDE + n0;
#pragma unroll
        for (int w = 0; w < 8; ++w) ((uint4*)op)[w] = *(uint4*)&ov[w * 4];
    }
}

// ---------------- per-row LN stats for layer 3 ----------------

template <int F>
__global__ void k_stats(const unsigned short* __restrict__ z, float2* __restrict__ st,
                        int mpad) {
    int row = blockIdx.x * 4 + (threadIdx.x >> 6);
    int lane = threadIdx.x & 63;
    const unsigned short* p = z + (size_t)row * F + lane * 8;
    uint4 u = *(const uint4*)p;
    float v[8]; unpack8(v, u);
    float s = 0.f, q = 0.f;
#pragma unroll
    for (int k = 0; k < 8; ++k) { s += v[k]; q += v[k] * v[k]; }
#pragma unroll
    for (int m = 1; m < 64; m <<= 1) {
        s += __shfl_xor(s, m);
        q += __shfl_xor(q, m);
    }
    if (lane == 0) {
        float mu = s * (1.0f / F);
        float var = q * (1.0f / F) - mu * mu;
        float2 o; o.x = mu; o.y = rsqrtf(var + 1e-5f);
        st[row] = o;
    }
}

// ---------------- pooling: LN fused, chunked partial sums + atomics ----------------

__global__ void k_pool3(const unsigned short* __restrict__ z, const float2* __restrict__ st,
                        const float* __restrict__ g, const float* __restrict__ be,
                        const int* __restrict__ batch, float* __restrict__ pooled, int n) {
    int i0 = blockIdx.x * PCH;
    int iend = i0 + PCH; if (iend > n) iend = n;
    int t = threadIdx.x;
    float g0 = g[t * 2], g1 = g[t * 2 + 1];
    float e0 = be[t * 2], e1 = be[t * 2 + 1];
    float s0 = 0.f, s1 = 0.f;
    int cur = batch[i0];
    for (int i = i0; i < iend; ++i) {
        int gg = batch[i];
        if (gg != cur) {
            atomicAdd(&pooled[(size_t)cur * 512 + t * 2], s0);
            atomicAdd(&pooled[(size_t)cur * 512 + t * 2 + 1], s1);
            s0 = s1 = 0.f;
            cur = gg;
        }
        float2 s2 = st[i];
        unsigned int u = *(const unsigned int*)(z + (size_t)i * 512 + t * 2);
        s0 += (b2f(u & 0xffffu) - s2.x) * s2.y * g0 + e0;
        s1 += (b2f(u >> 16) - s2.x) * s2.y * g1 + e1;
    }
    atomicAdd(&pooled[(size_t)cur * 512 + t * 2], s0);
    atomicAdd(&pooled[(size_t)cur * 512 + t * 2 + 1], s1);
}

// ---------------- final linear ----------------

__global__ void k_final(const float* __restrict__ pooled, const int* __restrict__ batch,
                        const float* __restrict__ Wf, const float* __restrict__ bf,
                        float* __restrict__ out, int n) {
    int gph = blockIdx.x;
    int o = threadIdx.x;
    int lo = 0, hi = n;
    while (lo < hi) { int mid = (lo + hi) >> 1; if (batch[mid] < gph) lo = mid + 1; else hi = mid; }
    int start = lo;
    lo = start; hi = n;
    while (lo < hi) { int mid = (lo + hi) >> 1; if (batch[mid] < gph + 1) lo = mid + 1; else hi = mid; }
    int end = lo;
    float inv = 1.0f / fmaxf((float)(end - start), 1.0f);

    __shared__ float p[512];
    for (int k = threadIdx.x; k < 512; k += 128) p[k] = pooled[(size_t)gph * 512 + k] * inv;
    __syncthreads();
    float acc = bf[o];
#pragma unroll 8
    for (int k = 0; k < 512; ++k) acc += p[k] * Wf[(size_t)k * 128 + o];
    out[(size_t)gph * 128 + o] = acc;
}

// ---------------- host ----------------

static inline size_t align_up(size_t x) { return (x + 255) & ~(size_t)255; }

extern "C" void kernel_launch(void* const* d_in, const int* in_sizes, int n_in,
                              void* d_out, int out_size, void* d_ws, size_t ws_size,
                              hipStream_t stream) {
    const float* x     = (const float*)d_in[0];
    const int*   ei    = (const int*)d_in[1];
    const int*   batch = (const int*)d_in[2];
    const float* W1 = (const float*)d_in[4],  *b1 = (const float*)d_in[5];
    const float* g1 = (const float*)d_in[6],  *be1= (const float*)d_in[7];
    const float* W2 = (const float*)d_in[8],  *b2 = (const float*)d_in[9];
    const float* g2 = (const float*)d_in[10], *be2= (const float*)d_in[11];
    const float* W3 = (const float*)d_in[12], *b3 = (const float*)d_in[13];
    const float* g3 = (const float*)d_in[14], *be3= (const float*)d_in[15];
    const float* Wf = (const float*)d_in[16], *bf = (const float*)d_in[17];
    float* out = (float*)d_out;

    const int N = in_sizes[0] / 128;   // 50000
    const int E = in_sizes[1] / 2;     // 800000
    const int Mpad = ((N + BM - 1) / BM) * BM;   // 50048
    const int* src = ei;
    const int* dst = ei + E;

    char* ws = (char*)d_ws;
    size_t off = 0;
    auto take = [&](size_t bytes) { char* p = ws + off; off += align_up(bytes); return p; };

    unsigned short* hT      = (unsigned short*)take((size_t)512 * HT_STRIDE * 2);  // 52.4 MB
    unsigned short* aggTb   = (unsigned short*)take((size_t)512 * HT_STRIDE * 2);  // 52.4 MB
    unsigned short* agg     = (unsigned short*)take((size_t)Mpad * 512 * 2);       // 51.2 MB
    unsigned short* zb      = (unsigned short*)take((size_t)Mpad * 512 * 2);       // 51.2 MB
    unsigned short* wt1     = (unsigned short*)take((size_t)256 * 128 * 2);
    unsigned short* wt2     = (unsigned short*)take((size_t)512 * 256 * 2);
    unsigned short* wt3     = (unsigned short*)take((size_t)512 * 512 * 2);
    float2*         st      = (float2*)take((size_t)Mpad * 8);
    float*          dinv    = (float*)take((size_t)N * 4);
    int*            rowstart= (int*)  take((size_t)(N + 1) * 4);
    int*            cnt     = (int*)  take((size_t)N * 4);
    int*            cursor  = (int*)  take((size_t)N * 4);
    int*            bsum    = (int*)  take((size_t)SCAN_B * 4);
    unsigned short* csrc16  = (unsigned short*)take((size_t)E * 2);
    float*          pooled  = (float*)take((size_t)GRAPHS * 512 * 4);
    unsigned short* xT      = (unsigned short*)zb;  // alias: xT dead before GEMM1 writes zb

    const int nb = (N + SCAN_B - 1) / SCAN_B;

    // CSR build (u16 source list; weights factorized into dinv)
    hipMemsetAsync(cnt, 0, (size_t)N * 4, stream);
    k_count<<<(E + 255) / 256, 256, 0, stream>>>(dst, cnt, E);
    k_scan1<<<nb, SCAN_B, 0, stream>>>(cnt, rowstart, bsum, N);
    k_scan2<<<1, SCAN_B, 0, stream>>>(bsum, nb);
    k_scan3<<<nb, SCAN_B, 0, stream>>>(rowstart, bsum, cnt, dinv, cursor, N, E);
    k_scatter_csr<<<(E + 255) / 256, 256, 0, stream>>>(src, dst, rowstart, cursor, csrc16, E);

    // weights -> bf16 transposed
    k_wt<<<(128 * 256 + 255) / 256, 256, 0, stream>>>(W1, wt1, 128, 256);
    k_wt<<<(256 * 512 + 255) / 256, 256, 0, stream>>>(W2, wt2, 256, 512);
    k_wt<<<(512 * 512 + 255) / 256, 256, 0, stream>>>(W3, wt3, 512, 512);

    // x -> x_T bf16 pre-scaled (needs dinv)
    k_x2bT<<<HT_STRIDE / 64, 256, 0, stream>>>(x, dinv, xT, N);

    // Layer 1
    k_aggT<<<128, 512, 0, stream>>>(xT, aggTb, rowstart, csrc16, dinv, N, Mpad);
    k_trT<<<dim3(Mpad / 64, 2), 256, 0, stream>>>(aggTb, agg, 128);
    k_gemm_bf16<<<(Mpad / BM) * 2, 256, 0, stream>>>(agg, wt1, b1, zb, 128, 256, 2);
    k_ln2t<256, true><<<HT_STRIDE / 64, 256, 0, stream>>>(zb, hT, g1, be1, dinv, N);

    // Layer 2
    k_aggT<<<256, 512, 0, stream>>>(hT, aggTb, rowstart, csrc16, dinv, N, Mpad);
    k_trT<<<dim3(Mpad / 64, 4), 256, 0, stream>>>(aggTb, agg, 256);
    k_gemm_bf16<<<(Mpad / BM) * 4, 256, 0, stream>>>(agg, wt2, b2, zb, 256, 512, 4);
    k_ln2t<512, true><<<HT_STRIDE / 64, 256, 0, stream>>>(zb, hT, g2, be2, dinv, N);

    // Layer 3
    k_aggT<<<512, 512, 0, stream>>>(hT, aggTb, rowstart, csrc16, dinv, N, Mpad);
    k_trT<<<dim3(Mpad / 64, 8), 256, 0, stream>>>(aggTb, agg, 512);
    k_gemm_bf16<<<(Mpad / BM) * 4, 256, 0, stream>>>(agg, wt3, b3, zb, 512, 512, 4);
    k_stats<512><<<Mpad / 4, 256, 0, stream>>>(zb, st, Mpad);

    // pool (LN fused) + final
    hipMemsetAsync(pooled, 0, (size_t)GRAPHS * 512 * 4, stream);
    k_pool3<<<(N + PCH - 1) / PCH, 256, 0, stream>>>(zb, st, g3, be3, batch, pooled, N);
    k_final<<<GRAPHS, 128, 0, stream>>>(pooled, batch, Wf, bf, out, N);
}

// Round 8
// 442.036 us; speedup vs baseline: 7.4709x; 7.4709x over previous
//
#include <hip/hip_runtime.h>
#include <hip/hip_bf16.h>
#include <math.h>

#define GRAPHS 128
#define SCAN_B 256
#define BM 128
#define BN 128
#define BK 64
#define PCH 128   // nodes per pooling block

typedef __attribute__((ext_vector_type(8))) short bfrag8;   // 8 bf16 (4 VGPRs)
typedef __attribute__((ext_vector_type(4))) float f32x4;

__device__ inline unsigned short f2b(float f) {
    unsigned int u = __float_as_uint(f);
    unsigned int r = (u + 0x7fffu + ((u >> 16) & 1u)) >> 16;  // RNE
    return (unsigned short)r;
}
__device__ inline float b2f(unsigned short u) {
    return __uint_as_float(((unsigned int)u) << 16);
}
__device__ inline void unpack8(float* v, uint4 u) {
    v[0] = b2f(u.x & 0xffffu); v[1] = b2f(u.x >> 16);
    v[2] = b2f(u.y & 0xffffu); v[3] = b2f(u.y >> 16);
    v[4] = b2f(u.z & 0xffffu); v[5] = b2f(u.z >> 16);
    v[6] = b2f(u.w & 0xffffu); v[7] = b2f(u.w >> 16);
}

__device__ inline void gload16(const void* g, void* l) {
    typedef unsigned int __attribute__((address_space(1))) gu32;
    typedef unsigned int __attribute__((address_space(3))) su32;
    __builtin_amdgcn_global_load_lds((const gu32*)g, (su32*)l, 16, 0, 0);
}

// bijective XCD chunk-major remap (m204)
__device__ inline int xcd_vid(int p, int nwg) {
    int q = nwg >> 3, r = nwg & 7, x = p & 7, ix = p >> 3;
    return (x < r ? x * (q + 1) : r * (q + 1) + (x - r) * q) + ix;
}

// ---------------- CSR build ----------------

__global__ void k_count(const int* __restrict__ dst, int* __restrict__ cnt, int E) {
    int i = blockIdx.x * blockDim.x + threadIdx.x;
    if (i < E) atomicAdd(&cnt[dst[i]], 1);
}

__global__ void k_scan1(const int* __restrict__ cnt, int* __restrict__ excl,
                        int* __restrict__ bsum, int n) {
    __shared__ int sh[SCAN_B];
    int t = threadIdx.x;
    int i = blockIdx.x * SCAN_B + t;
    int v = (i < n) ? cnt[i] : 0;
    sh[t] = v;
    __syncthreads();
    for (int off = 1; off < SCAN_B; off <<= 1) {
        int x = (t >= off) ? sh[t - off] : 0;
        __syncthreads();
        sh[t] += x;
        __syncthreads();
    }
    if (i < n) excl[i] = sh[t] - v;
    if (t == SCAN_B - 1) bsum[blockIdx.x] = sh[t];
}

__global__ void k_scan2(int* __restrict__ bsum, int nb) {
    __shared__ int sh[SCAN_B];
    int t = threadIdx.x;
    int v = (t < nb) ? bsum[t] : 0;
    sh[t] = v;
    __syncthreads();
    for (int off = 1; off < SCAN_B; off <<= 1) {
        int x = (t >= off) ? sh[t - off] : 0;
        __syncthreads();
        sh[t] += x;
        __syncthreads();
    }
    if (t < nb) bsum[t] = sh[t] - v;
}

__global__ void k_scan3(int* __restrict__ rowstart, const int* __restrict__ bsum,
                        const int* __restrict__ cnt, float* __restrict__ dinv,
                        int* __restrict__ cursor, int n, int E) {
    int i = blockIdx.x * SCAN_B + threadIdx.x;
    if (i < n) {
        rowstart[i] += bsum[blockIdx.x];
        cursor[i] = 0;
        dinv[i] = rsqrtf((float)cnt[i] + 1.0f);  // +1 self loop
    }
    if (i == 0) rowstart[n] = E;
}

__global__ void k_scatter_csr(const int* __restrict__ src, const int* __restrict__ dst,
                              const float* __restrict__ dinv, const int* __restrict__ rowstart,
                              int* __restrict__ cursor, int2* __restrict__ csr, int E) {
    int e = blockIdx.x * blockDim.x + threadIdx.x;
    if (e >= E) return;
    int s = src[e], d = dst[e];
    int pos = rowstart[d] + atomicAdd(&cursor[d], 1);
    int2 c;
    c.x = s;
    c.y = __float_as_int(dinv[s] * dinv[d]);
    csr[pos] = c;
}

// ---------------- weight transpose + bf16 cast: WT[n][k] = bf16(W[k][n]) ----------------

__global__ void k_wt(const float* __restrict__ W, unsigned short* __restrict__ WT,
                     int K, int N) {
    int idx = blockIdx.x * 256 + threadIdx.x;
    if (idx >= K * N) return;
    int k = idx / N, n2 = idx - k * N;
    WT[(size_t)n2 * K + k] = f2b(W[idx]);
}

// ---------------- x -> bf16 (padded rows zeroed) ----------------

__global__ void k_x2b(const float* __restrict__ x, unsigned short* __restrict__ xb,
                      int n, int mpad) {
    int idx = blockIdx.x * 256 + threadIdx.x;   // one float4 / thread
    if (idx >= mpad * 32) return;               // 128/4 quads per row
    int row = idx >> 5;
    float4 v = {0.f, 0.f, 0.f, 0.f};
    if (row < n) v = ((const float4*)x)[idx];
    ushort4 o;
    o.x = f2b(v.x); o.y = f2b(v.y); o.z = f2b(v.z); o.w = f2b(v.w);
    ((ushort4*)xb)[idx] = o;
}

// ---------------- bf16 aggregation (layer 1, R4-proven) ----------------

__device__ inline void acc8(float* a, uint4 u, float w) {
    a[0] += b2f(u.x & 0xffffu) * w; a[1] += b2f(u.x >> 16) * w;
    a[2] += b2f(u.y & 0xffffu) * w; a[3] += b2f(u.y >> 16) * w;
    a[4] += b2f(u.z & 0xffffu) * w; a[5] += b2f(u.z >> 16) * w;
    a[6] += b2f(u.w & 0xffffu) * w; a[7] += b2f(u.w >> 16) * w;
}

template <int F>
__global__ void k_aggb(const unsigned short* __restrict__ m, unsigned short* __restrict__ agg,
                       const int* __restrict__ rowstart, const int2* __restrict__ csr,
                       const float* __restrict__ dinv, int n, int mpad) {
    constexpr int TPN = F / 8;        // threads per node, 16B (8 bf16) each
    constexpr int NPB = 256 / TPN;
    int node = blockIdx.x * NPB + (int)(threadIdx.x / TPN);
    int fo = (int)(threadIdx.x % TPN) * 8;
    if (node >= mpad) return;
    uint4* dst = (uint4*)(agg + (size_t)node * F + fo);
    if (node >= n) { uint4 z = {0u, 0u, 0u, 0u}; *dst = z; return; }

    const unsigned short* mf = m + fo;
    float di = dinv[node];
    float a[8] = {};
    acc8(a, *(const uint4*)(mf + (size_t)node * F), di * di);  // self loop

    int b = rowstart[node], e = rowstart[node + 1];
    int j = b;
    for (; j + 4 <= e; j += 4) {
        int2 c0 = csr[j], c1 = csr[j + 1], c2 = csr[j + 2], c3 = csr[j + 3];
        uint4 u0 = *(const uint4*)(mf + (size_t)c0.x * F);
        uint4 u1 = *(const uint4*)(mf + (size_t)c1.x * F);
        uint4 u2 = *(const uint4*)(mf + (size_t)c2.x * F);
        uint4 u3 = *(const uint4*)(mf + (size_t)c3.x * F);
        acc8(a, u0, __int_as_float(c0.y));
        acc8(a, u1, __int_as_float(c1.y));
        acc8(a, u2, __int_as_float(c2.y));
        acc8(a, u3, __int_as_float(c3.y));
    }
    for (; j < e; ++j) {
        int2 c = csr[j];
        uint4 u = *(const uint4*)(mf + (size_t)c.x * F);
        acc8(a, u, __int_as_float(c.y));
    }
    uint4 o;
    o.x = (unsigned)f2b(a[0]) | ((unsigned)f2b(a[1]) << 16);
    o.y = (unsigned)f2b(a[2]) | ((unsigned)f2b(a[3]) << 16);
    o.z = (unsigned)f2b(a[4]) | ((unsigned)f2b(a[5]) << 16);
    o.w = (unsigned)f2b(a[6]) | ((unsigned)f2b(a[7]) << 16);
    *dst = o;
}

// ---------------- int8 aggregation (layers 2-3): gathers q8 rows + per-row scale ------

__device__ inline void acc8i(float* a, uint2 u, float w) {
    a[0] += (float)(signed char)(u.x) * w;
    a[1] += (float)(signed char)(u.x >> 8) * w;
    a[2] += (float)(signed char)(u.x >> 16) * w;
    a[3] += (float)(signed char)(u.x >> 24) * w;
    a[4] += (float)(signed char)(u.y) * w;
    a[5] += (float)(signed char)(u.y >> 8) * w;
    a[6] += (float)(signed char)(u.y >> 16) * w;
    a[7] += (float)(signed char)(u.y >> 24) * w;
}

template <int F>
__global__ void k_agg8(const signed char* __restrict__ q8, const float* __restrict__ scale,
                       unsigned short* __restrict__ agg, const int* __restrict__ rowstart,
                       const int2* __restrict__ csr, const float* __restrict__ dinv,
                       int n, int mpad) {
    constexpr int TPN = F / 8;        // threads per node, 8 int8 (8B) each
    constexpr int NPB = 256 / TPN;
    int node = blockIdx.x * NPB + (int)(threadIdx.x / TPN);
    int fo = (int)(threadIdx.x % TPN) * 8;
    if (node >= mpad) return;
    uint4* dst = (uint4*)(agg + (size_t)node * F + fo);
    if (node >= n) { uint4 z = {0u, 0u, 0u, 0u}; *dst = z; return; }

    const signed char* qf = q8 + fo;
    float di = dinv[node];
    float a[8] = {};
    {
        uint2 u = *(const uint2*)(qf + (size_t)node * F);
        acc8i(a, u, di * di * scale[node]);   // self loop
    }
    int b = rowstart[node], e = rowstart[node + 1];
    int j = b;
    for (; j + 2 <= e; j += 2) {
        int2 c0 = csr[j], c1 = csr[j + 1];
        uint2 u0 = *(const uint2*)(qf + (size_t)c0.x * F);
        uint2 u1 = *(const uint2*)(qf + (size_t)c1.x * F);
        float w0 = __int_as_float(c0.y) * scale[c0.x];
        float w1 = __int_as_float(c1.y) * scale[c1.x];
        acc8i(a, u0, w0);
        acc8i(a, u1, w1);
    }
    for (; j < e; ++j) {
        int2 c = csr[j];
        uint2 u = *(const uint2*)(qf + (size_t)c.x * F);
        acc8i(a, u, __int_as_float(c.y) * scale[c.x]);
    }
    uint4 o;
    o.x = (unsigned)f2b(a[0]) | ((unsigned)f2b(a[1]) << 16);
    o.y = (unsigned)f2b(a[2]) | ((unsigned)f2b(a[3]) << 16);
    o.z = (unsigned)f2b(a[4]) | ((unsigned)f2b(a[5]) << 16);
    o.w = (unsigned)f2b(a[6]) | ((unsigned)f2b(a[7]) << 16);
    *dst = o;
}

// ---------------- bf16 MFMA GEMM: Z = A @ BT^T + bias (bf16 out), XCD-chunked ----------

__global__ __launch_bounds__(256) void k_gemm_bf16(
    const unsigned short* __restrict__ A, const unsigned short* __restrict__ BT,
    const float* __restrict__ bias, unsigned short* __restrict__ C,
    int K, int N, int ncb) {
    __shared__ __align__(16) char sA[BM * BK * 2];
    __shared__ __align__(16) char sB[BN * BK * 2];

    const int vid = xcd_vid((int)blockIdx.x, (int)gridDim.x);
    const int rb = vid / ncb;
    const int cb = vid - rb * ncb;
    const int tid = threadIdx.x;
    const int lane = tid & 63;
    const int wave = tid >> 6;
    const int wr = wave >> 1, wc = wave & 1;
    const size_t row0 = (size_t)rb * BM;
    const size_t col0 = (size_t)cb * BN;

    const unsigned short* srcA[4];
    const unsigned short* srcB[4];
    char* dstA[4];
    char* dstB[4];
#pragma unroll
    for (int c = 0; c < 4; ++c) {
        int idx = c * 256 + tid;
        int row = idx >> 3;
        int cbl = ((idx & 7) << 4) ^ ((row & 7) << 4);
        srcA[c] = A + (row0 + row) * K + (cbl >> 1);
        srcB[c] = BT + (col0 + row) * K + (cbl >> 1);
        dstA[c] = sA + idx * 16;
        dstB[c] = sB + idx * 16;
    }

    const int fr = lane & 15;
    const int fg = lane >> 4;
    const int fsw = (lane & 7) << 4;
    int offA[4][2], offB[4][2];
#pragma unroll
    for (int t = 0; t < 4; ++t)
#pragma unroll
        for (int kk = 0; kk < 2; ++kk) {
            offA[t][kk] = (wr * 64 + t * 16 + fr) * (BK * 2) + ((kk * 64 + fg * 16) ^ fsw);
            offB[t][kk] = (wc * 64 + t * 16 + fr) * (BK * 2) + ((kk * 64 + fg * 16) ^ fsw);
        }

    f32x4 acc[4][4] = {};

    for (int k0 = 0; k0 < K; k0 += BK) {
#pragma unroll
        for (int c = 0; c < 4; ++c) gload16(srcA[c] + k0, dstA[c]);
#pragma unroll
        for (int c = 0; c < 4; ++c) gload16(srcB[c] + k0, dstB[c]);
        __syncthreads();
#pragma unroll
        for (int kk = 0; kk < 2; ++kk) {
            bfrag8 av[4], bv[4];
#pragma unroll
            for (int t = 0; t < 4; ++t) av[t] = *(const bfrag8*)(sA + offA[t][kk]);
#pragma unroll
            for (int t = 0; t < 4; ++t) bv[t] = *(const bfrag8*)(sB + offB[t][kk]);
#pragma unroll
            for (int i = 0; i < 4; ++i)
#pragma unroll
                for (int j = 0; j < 4; ++j)
                    acc[i][j] = __builtin_amdgcn_mfma_f32_16x16x32_bf16(av[i], bv[j],
                                                                        acc[i][j], 0, 0, 0);
        }
        __syncthreads();
    }

#pragma unroll
    for (int i = 0; i < 4; ++i) {
#pragma unroll
        for (int j = 0; j < 4; ++j) {
            size_t r = row0 + wr * 64 + i * 16 + fg * 4;
            size_t cc = col0 + wc * 64 + j * 16 + fr;
            float bb = bias[cc];
#pragma unroll
            for (int q = 0; q < 4; ++q)
                C[(r + q) * N + cc] = f2b(acc[i][j][q] + bb);
        }
    }
}

// ---------------- LN + LeakyReLU -> int8 rows with per-row scale, wave per row --------

template <int F, bool LRELU>
__global__ void k_lnr8(const unsigned short* __restrict__ z, signed char* __restrict__ q8,
                       float* __restrict__ scale, const float* __restrict__ g,
                       const float* __restrict__ be, int mpad) {
    constexpr int V = F / 64;   // 4 (F=256) or 8 (F=512)
    int row = blockIdx.x * 4 + (threadIdx.x >> 6);
    int lane = threadIdx.x & 63;
    const unsigned short* p = z + (size_t)row * F + lane * V;
    float v[V];
    if constexpr (V == 8) {
        uint4 u = *(const uint4*)p;
        unpack8(v, u);
    } else {
        uint2 u = *(const uint2*)p;
        v[0] = b2f(u.x & 0xffffu); v[1] = b2f(u.x >> 16);
        v[2] = b2f(u.y & 0xffffu); v[3] = b2f(u.y >> 16);
    }
    float s = 0.f, q = 0.f;
#pragma unroll
    for (int k = 0; k < V; ++k) { s += v[k]; q += v[k] * v[k]; }
#pragma unroll
    for (int m = 1; m < 64; m <<= 1) {
        s += __shfl_xor(s, m);
        q += __shfl_xor(q, m);
    }
    float mu = s * (1.0f / F);
    float var = q * (1.0f / F) - mu * mu;
    float rs = rsqrtf(var + 1e-5f);

    float y[V];
    float mx = 0.f;
#pragma unroll
    for (int k = 0; k < V; ++k) {
        float yy = (v[k] - mu) * rs * g[lane * V + k] + be[lane * V + k];
        if (LRELU) yy = fmaxf(yy, 0.f) + 0.01f * fminf(yy, 0.f);
        y[k] = yy;
        mx = fmaxf(mx, fabsf(yy));
    }
#pragma unroll
    for (int m = 1; m < 64; m <<= 1) mx = fmaxf(mx, __shfl_xor(mx, m));

    float inv = (mx > 0.f) ? 127.0f / mx : 0.f;
    unsigned int ob[V / 4];
#pragma unroll
    for (int k = 0; k < V; k += 4) {
        int q0 = __float2int_rn(y[k] * inv);
        int q1 = __float2int_rn(y[k + 1] * inv);
        int q2 = __float2int_rn(y[k + 2] * inv);
        int q3 = __float2int_rn(y[k + 3] * inv);
        ob[k / 4] = (q0 & 0xff) | ((q1 & 0xff) << 8) | ((q2 & 0xff) << 16) | ((q3 & 0xff) << 24);
    }
    signed char* qp = q8 + (size_t)row * F + lane * V;
    if constexpr (V == 8) *(uint2*)qp = *(uint2*)ob;
    else                  *(unsigned int*)qp = ob[0];
    if (lane == 0) scale[row] = mx * (1.0f / 127.0f);
}

// ---------------- per-row LN stats for layer 3 ----------------

template <int F>
__global__ void k_stats(const unsigned short* __restrict__ z, float2* __restrict__ st,
                        int mpad) {
    int row = blockIdx.x * 4 + (threadIdx.x >> 6);
    int lane = threadIdx.x & 63;
    const unsigned short* p = z + (size_t)row * F + lane * 8;
    uint4 u = *(const uint4*)p;
    float v[8]; unpack8(v, u);
    float s = 0.f, q = 0.f;
#pragma unroll
    for (int k = 0; k < 8; ++k) { s += v[k]; q += v[k] * v[k]; }
#pragma unroll
    for (int m = 1; m < 64; m <<= 1) {
        s += __shfl_xor(s, m);
        q += __shfl_xor(q, m);
    }
    if (lane == 0) {
        float mu = s * (1.0f / F);
        float var = q * (1.0f / F) - mu * mu;
        float2 o; o.x = mu; o.y = rsqrtf(var + 1e-5f);
        st[row] = o;
    }
}

// ---------------- pooling: LN fused, chunked partial sums + atomics ----------------

__global__ void k_pool3(const unsigned short* __restrict__ z, const float2* __restrict__ st,
                        const float* __restrict__ g, const float* __restrict__ be,
                        const int* __restrict__ batch, float* __restrict__ pooled, int n) {
    int i0 = blockIdx.x * PCH;
    int iend = i0 + PCH; if (iend > n) iend = n;
    int t = threadIdx.x;
    float g0 = g[t * 2], g1 = g[t * 2 + 1];
    float e0 = be[t * 2], e1 = be[t * 2 + 1];
    float s0 = 0.f, s1 = 0.f;
    int cur = batch[i0];
    for (int i = i0; i < iend; ++i) {
        int gg = batch[i];
        if (gg != cur) {
            atomicAdd(&pooled[(size_t)cur * 512 + t * 2], s0);
            atomicAdd(&pooled[(size_t)cur * 512 + t * 2 + 1], s1);
            s0 = s1 = 0.f;
            cur = gg;
        }
        float2 s2 = st[i];
        unsigned int u = *(const unsigned int*)(z + (size_t)i * 512 + t * 2);
        s0 += (b2f(u & 0xffffu) - s2.x) * s2.y * g0 + e0;
        s1 += (b2f(u >> 16) - s2.x) * s2.y * g1 + e1;
    }
    atomicAdd(&pooled[(size_t)cur * 512 + t * 2], s0);
    atomicAdd(&pooled[(size_t)cur * 512 + t * 2 + 1], s1);
}

// ---------------- final linear ----------------

__global__ void k_final(const float* __restrict__ pooled, const int* __restrict__ batch,
                        const float* __restrict__ Wf, const float* __restrict__ bf,
                        float* __restrict__ out, int n) {
    int gph = blockIdx.x;
    int o = threadIdx.x;
    int lo = 0, hi = n;
    while (lo < hi) { int mid = (lo + hi) >> 1; if (batch[mid] < gph) lo = mid + 1; else hi = mid; }
    int start = lo;
    lo = start; hi = n;
    while (lo < hi) { int mid = (lo + hi) >> 1; if (batch[mid] < gph + 1) lo = mid + 1; else hi = mid; }
    int end = lo;
    float inv = 1.0f / fmaxf((float)(end - start), 1.0f);

    __shared__ float p[512];
    for (int k = threadIdx.x; k < 512; k += 128) p[k] = pooled[(size_t)gph * 512 + k] * inv;
    __syncthreads();
    float acc = bf[o];
#pragma unroll 8
    for (int k = 0; k < 512; ++k) acc += p[k] * Wf[(size_t)k * 128 + o];
    out[(size_t)gph * 128 + o] = acc;
}

// ---------------- host ----------------

static inline size_t align_up(size_t x) { return (x + 255) & ~(size_t)255; }

extern "C" void kernel_launch(void* const* d_in, const int* in_sizes, int n_in,
                              void* d_out, int out_size, void* d_ws, size_t ws_size,
                              hipStream_t stream) {
    const float* x     = (const float*)d_in[0];
    const int*   ei    = (const int*)d_in[1];
    const int*   batch = (const int*)d_in[2];
    const float* W1 = (const float*)d_in[4],  *b1 = (const float*)d_in[5];
    const float* g1 = (const float*)d_in[6],  *be1= (const float*)d_in[7];
    const float* W2 = (const float*)d_in[8],  *b2 = (const float*)d_in[9];
    const float* g2 = (const float*)d_in[10], *be2= (const float*)d_in[11];
    const float* W3 = (const float*)d_in[12], *b3 = (const float*)d_in[13];
    const float* g3 = (const float*)d_in[14], *be3= (const float*)d_in[15];
    const float* Wf = (const float*)d_in[16], *bf = (const float*)d_in[17];
    float* out = (float*)d_out;

    const int N = in_sizes[0] / 128;   // 50000
    const int E = in_sizes[1] / 2;     // 800000
    const int Mpad = ((N + BM - 1) / BM) * BM;   // 50048
    const int* src = ei;
    const int* dst = ei + E;

    char* ws = (char*)d_ws;
    size_t off = 0;
    auto take = [&](size_t bytes) { char* p = ws + off; off += align_up(bytes); return p; };

    unsigned short* zb      = (unsigned short*)take((size_t)Mpad * 512 * 2);  // GEMM out
    unsigned short* aggb    = (unsigned short*)take((size_t)Mpad * 512 * 2);  // agg out
    signed char*    q8      = (signed char*)take((size_t)Mpad * 512);         // int8 act
    float*          scale   = (float*)take((size_t)Mpad * 4);
    unsigned short* xb      = (unsigned short*)take((size_t)Mpad * 128 * 2);
    unsigned short* wt1     = (unsigned short*)take((size_t)256 * 128 * 2);
    unsigned short* wt2     = (unsigned short*)take((size_t)512 * 256 * 2);
    unsigned short* wt3     = (unsigned short*)take((size_t)512 * 512 * 2);
    float2*         st      = (float2*)take((size_t)Mpad * 8);
    float*          dinv    = (float*)take((size_t)N * 4);
    int*            rowstart= (int*)  take((size_t)(N + 1) * 4);
    int*            cnt     = (int*)  take((size_t)N * 4);
    int*            cursor  = (int*)  take((size_t)N * 4);
    int*            bsum    = (int*)  take((size_t)SCAN_B * 4);
    int2*           csr     = (int2*) take((size_t)E * 8);
    float*          pooled  = (float*)take((size_t)GRAPHS * 512 * 4);

    const int nb = (N + SCAN_B - 1) / SCAN_B;
    const int NR4 = Mpad / 4;

    // CSR build
    hipMemsetAsync(cnt, 0, (size_t)N * 4, stream);
    k_count<<<(E + 255) / 256, 256, 0, stream>>>(dst, cnt, E);
    k_scan1<<<nb, SCAN_B, 0, stream>>>(cnt, rowstart, bsum, N);
    k_scan2<<<1, SCAN_B, 0, stream>>>(bsum, nb);
    k_scan3<<<nb, SCAN_B, 0, stream>>>(rowstart, bsum, cnt, dinv, cursor, N, E);
    k_scatter_csr<<<(E + 255) / 256, 256, 0, stream>>>(src, dst, dinv, rowstart, cursor, csr, E);

    // weights -> bf16 transposed
    k_wt<<<(128 * 256 + 255) / 256, 256, 0, stream>>>(W1, wt1, 128, 256);
    k_wt<<<(256 * 512 + 255) / 256, 256, 0, stream>>>(W2, wt2, 256, 512);
    k_wt<<<(512 * 512 + 255) / 256, 256, 0, stream>>>(W3, wt3, 512, 512);

    // x -> bf16 (padded)
    k_x2b<<<(Mpad * 32 + 255) / 256, 256, 0, stream>>>(x, xb, N, Mpad);

    // Layer 1: bf16 gather -> GEMM(K=128,N=256) -> LN+lrelu -> int8
    k_aggb<128><<<Mpad / 16, 256, 0, stream>>>(xb, aggb, rowstart, csr, dinv, N, Mpad);
    k_gemm_bf16<<<(Mpad / BM) * 2, 256, 0, stream>>>(aggb, wt1, b1, zb, 128, 256, 2);
    k_lnr8<256, true><<<NR4, 256, 0, stream>>>(zb, q8, scale, g1, be1, Mpad);

    // Layer 2: int8 gather -> GEMM(K=256,N=512) -> LN+lrelu -> int8
    k_agg8<256><<<Mpad / 8, 256, 0, stream>>>(q8, scale, aggb, rowstart, csr, dinv, N, Mpad);
    k_gemm_bf16<<<(Mpad / BM) * 4, 256, 0, stream>>>(aggb, wt2, b2, zb, 256, 512, 4);
    k_lnr8<512, true><<<NR4, 256, 0, stream>>>(zb, q8, scale, g2, be2, Mpad);

    // Layer 3: int8 gather -> GEMM(K=512,N=512) -> stats (LN fused into pool)
    k_agg8<512><<<Mpad / 4, 256, 0, stream>>>(q8, scale, aggb, rowstart, csr, dinv, N, Mpad);
    k_gemm_bf16<<<(Mpad / BM) * 4, 256, 0, stream>>>(aggb, wt3, b3, zb, 512, 512, 4);
    k_stats<512><<<NR4, 256, 0, stream>>>(zb, st, Mpad);

    // pool (LN fused) + final
    hipMemsetAsync(pooled, 0, (size_t)GRAPHS * 512 * 4, stream);
    k_pool3<<<(N + PCH - 1) / PCH, 256, 0, stream>>>(zb, st, g3, be3, batch, pooled, N);
    k_final<<<GRAPHS, 128, 0, stream>>>(pooled, batch, Wf, bf, out, N);
}